// Round 1
// baseline (1062.049 us; speedup 1.0000x reference)
//
#include <hip/hip_runtime.h>
#include <hip/hip_bf16.h>

#define DIM 128
#define TILE_R 32

// ---------------------------------------------------------------------------
// Generic [N x 128] @ [128 x 128] GEMM with fused epilogues.
// MODE 0: C = A @ W
// MODE 1: C = (A @ W) * (1/max(rowsum[r],1e-8)) + bias      (agg @ Wm + bm)
// MODE 2: C = LayerNorm(A @ W + bias + resid) * gamma + beta
// Block: 256 threads, tile 32 rows x 128 cols, per-thread 4x4 register block.
// W staged in LDS (64KB), A tile staged in LDS (16KB).
// ---------------------------------------------------------------------------
template<int MODE>
__global__ __launch_bounds__(256) void gemm128(
    const float* __restrict__ A, const float* __restrict__ W,
    const float* __restrict__ bias, const float* __restrict__ rowsum,
    const float* __restrict__ resid, const float* __restrict__ gamma,
    const float* __restrict__ beta, float* __restrict__ C, int N)
{
    __shared__ float Ws[128 * 128];
    __shared__ float As[TILE_R * 128];
    const int t = threadIdx.x;

    // Stage W (16384 floats): 16 float4 per thread, coalesced.
#pragma unroll
    for (int i = 0; i < 16; ++i) {
        const int idx = (i * 256 + t) * 4;
        *(float4*)&Ws[idx] = *(const float4*)&W[idx];
    }

    const int r0 = blockIdx.x * TILE_R;
    // Stage A tile: thread t -> row t>>3, 16 consecutive cols at (t&7)*16.
    {
        const int r = t >> 3, c = (t & 7) * 16;
        const int row = r0 + r;
        if (row < N) {
#pragma unroll
            for (int i = 0; i < 4; ++i)
                *(float4*)&As[r * 128 + c + i * 4] =
                    *(const float4*)&A[(size_t)row * 128 + c + i * 4];
        } else {
#pragma unroll
            for (int i = 0; i < 4; ++i)
                *(float4*)&As[r * 128 + c + i * 4] = make_float4(0.f, 0.f, 0.f, 0.f);
        }
    }
    __syncthreads();

    const int ty = t >> 5, tx = t & 31;   // ty in [0,8): row group; tx in [0,32): col group
    const int c0 = tx * 4;
    float acc[4][4] = {};

#pragma unroll 4
    for (int k = 0; k < 128; ++k) {
        const float4 b = *(const float4*)&Ws[k * 128 + c0];
        float a[4];
#pragma unroll
        for (int i = 0; i < 4; ++i) a[i] = As[(ty * 4 + i) * 128 + k];
#pragma unroll
        for (int i = 0; i < 4; ++i) {
            acc[i][0] += a[i] * b.x;
            acc[i][1] += a[i] * b.y;
            acc[i][2] += a[i] * b.z;
            acc[i][3] += a[i] * b.w;
        }
    }

    if (MODE == 0) {
#pragma unroll
        for (int i = 0; i < 4; ++i) {
            const int row = r0 + ty * 4 + i;
            if (row < N)
                *(float4*)&C[(size_t)row * 128 + c0] =
                    make_float4(acc[i][0], acc[i][1], acc[i][2], acc[i][3]);
        }
    } else if (MODE == 1) {
        const float4 bv = *(const float4*)&bias[c0];
#pragma unroll
        for (int i = 0; i < 4; ++i) {
            const int row = r0 + ty * 4 + i;
            if (row < N) {
                const float rs = 1.0f / fmaxf(rowsum[row], 1e-8f);
                *(float4*)&C[(size_t)row * 128 + c0] =
                    make_float4(acc[i][0] * rs + bv.x, acc[i][1] * rs + bv.y,
                                acc[i][2] * rs + bv.z, acc[i][3] * rs + bv.w);
            }
        }
    } else {
        // MODE 2: h = acc + bias + resid; stage h into As; then per-row LN.
        const float4 bv = *(const float4*)&bias[c0];
        __syncthreads();   // all As reads from the K-loop are done
#pragma unroll
        for (int i = 0; i < 4; ++i) {
            const int row = r0 + ty * 4 + i;
            float4 rv = make_float4(0.f, 0.f, 0.f, 0.f);
            if (row < N) rv = *(const float4*)&resid[(size_t)row * 128 + c0];
            *(float4*)&As[(ty * 4 + i) * 128 + c0] =
                make_float4(acc[i][0] + bv.x + rv.x, acc[i][1] + bv.y + rv.y,
                            acc[i][2] + bv.z + rv.z, acc[i][3] + bv.w + rv.w);
        }
        __syncthreads();
        const int r = t >> 3, cc = (t & 7) * 16;
        const int row = r0 + r;
        float v[16];
        float sum = 0.f, sq = 0.f;
#pragma unroll
        for (int m = 0; m < 16; ++m) {
            v[m] = As[r * 128 + cc + m];
            sum += v[m];
            sq += v[m] * v[m];
        }
        // reduce across the 8 lanes that share this row
#pragma unroll
        for (int off = 4; off; off >>= 1) {
            sum += __shfl_xor(sum, off);
            sq  += __shfl_xor(sq, off);
        }
        const float mu = sum * (1.0f / 128.0f);
        const float var = sq * (1.0f / 128.0f) - mu * mu;
        const float rstd = rsqrtf(var + 1e-5f);
        if (row < N) {
#pragma unroll
            for (int m = 0; m < 16; ++m)
                v[m] = (v[m] - mu) * rstd * gamma[cc + m] + beta[cc + m];
#pragma unroll
            for (int m = 0; m < 4; ++m)
                *(float4*)&C[(size_t)row * 128 + cc + m * 4] =
                    make_float4(v[m * 4], v[m * 4 + 1], v[m * 4 + 2], v[m * 4 + 3]);
        }
    }
}

// ---------------------------------------------------------------------------
// Per-edge attention + atomic scatter-add aggregation.
// One wave (64 lanes) per edge; lane handles dims {2l, 2l+1}.
// ---------------------------------------------------------------------------
__global__ __launch_bounds__(256) void edge_kernel(
    const int* __restrict__ src, const int* __restrict__ dst,
    const float* __restrict__ K, const float* __restrict__ Q,
    const float* __restrict__ V, const float* __restrict__ Wa,
    float* __restrict__ msg, float* __restrict__ wsum, int E)
{
    const int e = (int)((blockIdx.x * blockDim.x + threadIdx.x) >> 6);
    if (e >= E) return;
    const int lane = threadIdx.x & 63;
    const int s = src[e], d = dst[e];

    const float2 ek = *(const float2*)&K[(size_t)s * 128 + lane * 2];
    const float2 eq = *(const float2*)&Q[(size_t)d * 128 + lane * 2];
    const float2 ev = *(const float2*)&V[(size_t)s * 128 + lane * 2];

    // per-head dot product: head = lane>>4, reduce over 16-lane groups
    float p = ek.x * eq.x + ek.y * eq.y;
#pragma unroll
    for (int off = 8; off; off >>= 1) p += __shfl_xor(p, off);

    // ek @ Wa term: full 128-dim reduction for each of 4 heads
    const float4 wa0 = *(const float4*)&Wa[(lane * 2) * 4];
    const float4 wa1 = *(const float4*)&Wa[(lane * 2 + 1) * 4];
    float s0 = ek.x * wa0.x + ek.y * wa1.x;
    float s1 = ek.x * wa0.y + ek.y * wa1.y;
    float s2 = ek.x * wa0.z + ek.y * wa1.z;
    float s3 = ek.x * wa0.w + ek.y * wa1.w;
#pragma unroll
    for (int off = 32; off; off >>= 1) {
        s0 += __shfl_xor(s0, off);
        s1 += __shfl_xor(s1, off);
        s2 += __shfl_xor(s2, off);
        s3 += __shfl_xor(s3, off);
    }

    const float inv = 0.17677669529663687f;  // 1/sqrt(32)
    const float sc0 = __shfl(p, 0)  * inv + s0;
    const float sc1 = __shfl(p, 16) * inv + s1;
    const float sc2 = __shfl(p, 32) * inv + s2;
    const float sc3 = __shfl(p, 48) * inv + s3;

    const float m = fmaxf(fmaxf(sc0, sc1), fmaxf(sc2, sc3));
    const float e0 = __expf(sc0 - m);
    const float e1 = __expf(sc1 - m);
    const float e2 = __expf(sc2 - m);
    const float e3 = __expf(sc3 - m);
    const float rsum = 1.0f / (e0 + e1 + e2 + e3);
    const float a0 = e0 * rsum, a1 = e1 * rsum, a2 = e2 * rsum, a3 = e3 * rsum;

    const int h = lane >> 4;
    const float att = (h == 0) ? a0 : (h == 1) ? a1 : (h == 2) ? a2 : a3;

    atomicAdd(&msg[(size_t)d * 128 + lane * 2],     att * ev.x);
    atomicAdd(&msg[(size_t)d * 128 + lane * 2 + 1], att * ev.y);
    if (lane == 0) atomicAdd(&wsum[d], a0 + a1 + a2 + a3);
}

// ---------------------------------------------------------------------------
extern "C" void kernel_launch(void* const* d_in, const int* in_sizes, int n_in,
                              void* d_out, int out_size, void* d_ws, size_t ws_size,
                              hipStream_t stream)
{
    const float* x_user  = (const float*)d_in[0];
    const float* x_item  = (const float*)d_in[1];
    const int*   ei_ui   = (const int*)d_in[2];
    const int*   ei_iu   = (const int*)d_in[3];
    const float* Wk_user = (const float*)d_in[4];
    const float* Wq_user = (const float*)d_in[5];
    const float* Wv_user = (const float*)d_in[6];
    const float* Wk_item = (const float*)d_in[7];
    const float* Wq_item = (const float*)d_in[8];
    const float* Wv_item = (const float*)d_in[9];
    const float* Wa_ui   = (const float*)d_in[10];
    const float* Wa_iu   = (const float*)d_in[11];
    const float* Wm_user = (const float*)d_in[12];
    const float* bm_user = (const float*)d_in[13];
    const float* Wm_item = (const float*)d_in[14];
    const float* bm_item = (const float*)d_in[15];
    const float* Wg_user = (const float*)d_in[16];
    const float* bg_user = (const float*)d_in[17];
    const float* Wg_item = (const float*)d_in[18];
    const float* bg_item = (const float*)d_in[19];
    const float* lng_user = (const float*)d_in[20];
    const float* lnb_user = (const float*)d_in[21];
    const float* lng_item = (const float*)d_in[22];
    const float* lnb_item = (const float*)d_in[23];

    const int n_user = in_sizes[0] / DIM;
    const int n_item = in_sizes[1] / DIM;
    const int E = in_sizes[2] / 2;

    const size_t nf_i = (size_t)n_item * DIM;
    const size_t nf_u = (size_t)n_user * DIM;
    const size_t nf_max = (nf_i > nf_u) ? nf_i : nf_u;

    float* ws = (float*)d_ws;
    float* msg_i  = ws;                 // [n_item,128]
    float* msg_u  = msg_i + nf_i;       // [n_user,128]
    float* wsum_i = msg_u + nf_u;       // [n_item]
    float* wsum_u = wsum_i + n_item;    // [n_user]
    float* bufK   = wsum_u + n_user;    // [nmax,128]
    float* bufV   = bufK + nf_max;      // [nmax,128]
    float* bufQ   = bufV + nf_max;      // [nmax,128]
    float* tmp    = bufK;               // reused after both edge phases

    float* out_user = (float*)d_out;
    float* out_item = out_user + nf_u;

    // zero the accumulation buffers (msg_i, msg_u, wsum_i, wsum_u contiguous)
    hipMemsetAsync(d_ws, 0, (nf_i + nf_u + n_item + n_user) * sizeof(float), stream);

    const dim3 blk(256);
    const int grid_u = (n_user + TILE_R - 1) / TILE_R;
    const int grid_i = (n_item + TILE_R - 1) / TILE_R;
    const int grid_e = (E + 3) / 4;   // 4 waves (edges) per 256-thread block

    // Phase A: dst=item needs k_user, v_user, q_item
    gemm128<0><<<grid_u, blk, 0, stream>>>(x_user, Wk_user, nullptr, nullptr, nullptr, nullptr, nullptr, bufK, n_user);
    gemm128<0><<<grid_u, blk, 0, stream>>>(x_user, Wv_user, nullptr, nullptr, nullptr, nullptr, nullptr, bufV, n_user);
    gemm128<0><<<grid_i, blk, 0, stream>>>(x_item, Wq_item, nullptr, nullptr, nullptr, nullptr, nullptr, bufQ, n_item);
    edge_kernel<<<grid_e, blk, 0, stream>>>(ei_ui, ei_ui + E, bufK, bufQ, bufV, Wa_ui, msg_i, wsum_i, E);

    // Phase B: dst=user needs k_item, v_item, q_user (reuse buffers)
    gemm128<0><<<grid_i, blk, 0, stream>>>(x_item, Wk_item, nullptr, nullptr, nullptr, nullptr, nullptr, bufK, n_item);
    gemm128<0><<<grid_i, blk, 0, stream>>>(x_item, Wv_item, nullptr, nullptr, nullptr, nullptr, nullptr, bufV, n_item);
    gemm128<0><<<grid_u, blk, 0, stream>>>(x_user, Wq_user, nullptr, nullptr, nullptr, nullptr, nullptr, bufQ, n_user);
    edge_kernel<<<grid_e, blk, 0, stream>>>(ei_iu, ei_iu + E, bufK, bufQ, bufV, Wa_iu, msg_u, wsum_u, E);

    // Post item: tmp = (msg_i @ Wm_item)/clip(wsum_i) + bm_item; out_item = LN(tmp @ Wg_item + bg_item + x_item)
    gemm128<1><<<grid_i, blk, 0, stream>>>(msg_i, Wm_item, bm_item, wsum_i, nullptr, nullptr, nullptr, tmp, n_item);
    gemm128<2><<<grid_i, blk, 0, stream>>>(tmp, Wg_item, bg_item, nullptr, x_item, lng_item, lnb_item, out_item, n_item);

    // Post user
    gemm128<1><<<grid_u, blk, 0, stream>>>(msg_u, Wm_user, bm_user, wsum_u, nullptr, nullptr, nullptr, tmp, n_user);
    gemm128<2><<<grid_u, blk, 0, stream>>>(tmp, Wg_user, bg_user, nullptr, x_user, lng_user, lnb_user, out_user, n_user);
}

// Round 2
// 629.001 us; speedup vs baseline: 1.6885x; 1.6885x over previous
//
#include <hip/hip_runtime.h>
#include <hip/hip_bf16.h>

#define DIM 128
#define TILE_R 32

// ---------------------------------------------------------------------------
// Generic [N x 128] @ [128 x 128] GEMM with fused epilogues.
// MODE 0: C = A @ W
// MODE 1: C = (A @ W) * (1/max(rowsum[r],1e-8)) + bias      (agg @ Wm + bm)
// MODE 2: C = LayerNorm(A @ W + bias + resid) * gamma + beta
// ---------------------------------------------------------------------------
template<int MODE>
__global__ __launch_bounds__(256) void gemm128(
    const float* __restrict__ A, const float* __restrict__ W,
    const float* __restrict__ bias, const float* __restrict__ rowsum,
    const float* __restrict__ resid, const float* __restrict__ gamma,
    const float* __restrict__ beta, float* __restrict__ C, int N)
{
    __shared__ float Ws[128 * 128];
    __shared__ float As[TILE_R * 128];
    const int t = threadIdx.x;

#pragma unroll
    for (int i = 0; i < 16; ++i) {
        const int idx = (i * 256 + t) * 4;
        *(float4*)&Ws[idx] = *(const float4*)&W[idx];
    }

    const int r0 = blockIdx.x * TILE_R;
    {
        const int r = t >> 3, c = (t & 7) * 16;
        const int row = r0 + r;
        if (row < N) {
#pragma unroll
            for (int i = 0; i < 4; ++i)
                *(float4*)&As[r * 128 + c + i * 4] =
                    *(const float4*)&A[(size_t)row * 128 + c + i * 4];
        } else {
#pragma unroll
            for (int i = 0; i < 4; ++i)
                *(float4*)&As[r * 128 + c + i * 4] = make_float4(0.f, 0.f, 0.f, 0.f);
        }
    }
    __syncthreads();

    const int ty = t >> 5, tx = t & 31;
    const int c0 = tx * 4;
    float acc[4][4] = {};

#pragma unroll 4
    for (int k = 0; k < 128; ++k) {
        const float4 b = *(const float4*)&Ws[k * 128 + c0];
        float a[4];
#pragma unroll
        for (int i = 0; i < 4; ++i) a[i] = As[(ty * 4 + i) * 128 + k];
#pragma unroll
        for (int i = 0; i < 4; ++i) {
            acc[i][0] += a[i] * b.x;
            acc[i][1] += a[i] * b.y;
            acc[i][2] += a[i] * b.z;
            acc[i][3] += a[i] * b.w;
        }
    }

    if (MODE == 0) {
#pragma unroll
        for (int i = 0; i < 4; ++i) {
            const int row = r0 + ty * 4 + i;
            if (row < N)
                *(float4*)&C[(size_t)row * 128 + c0] =
                    make_float4(acc[i][0], acc[i][1], acc[i][2], acc[i][3]);
        }
    } else if (MODE == 1) {
        const float4 bv = *(const float4*)&bias[c0];
#pragma unroll
        for (int i = 0; i < 4; ++i) {
            const int row = r0 + ty * 4 + i;
            if (row < N) {
                const float rs = 1.0f / fmaxf(rowsum[row], 1e-8f);
                *(float4*)&C[(size_t)row * 128 + c0] =
                    make_float4(acc[i][0] * rs + bv.x, acc[i][1] * rs + bv.y,
                                acc[i][2] * rs + bv.z, acc[i][3] * rs + bv.w);
            }
        }
    } else {
        const float4 bv = *(const float4*)&bias[c0];
        __syncthreads();
#pragma unroll
        for (int i = 0; i < 4; ++i) {
            const int row = r0 + ty * 4 + i;
            float4 rv = make_float4(0.f, 0.f, 0.f, 0.f);
            if (row < N) rv = *(const float4*)&resid[(size_t)row * 128 + c0];
            *(float4*)&As[(ty * 4 + i) * 128 + c0] =
                make_float4(acc[i][0] + bv.x + rv.x, acc[i][1] + bv.y + rv.y,
                            acc[i][2] + bv.z + rv.z, acc[i][3] + bv.w + rv.w);
        }
        __syncthreads();
        const int r = t >> 3, cc = (t & 7) * 16;
        const int row = r0 + r;
        float v[16];
        float sum = 0.f, sq = 0.f;
#pragma unroll
        for (int m = 0; m < 16; ++m) {
            v[m] = As[r * 128 + cc + m];
            sum += v[m];
            sq += v[m] * v[m];
        }
#pragma unroll
        for (int off = 4; off; off >>= 1) {
            sum += __shfl_xor(sum, off);
            sq  += __shfl_xor(sq, off);
        }
        const float mu = sum * (1.0f / 128.0f);
        const float var = sq * (1.0f / 128.0f) - mu * mu;
        const float rstd = rsqrtf(var + 1e-5f);
        if (row < N) {
#pragma unroll
            for (int m = 0; m < 16; ++m)
                v[m] = (v[m] - mu) * rstd * gamma[cc + m] + beta[cc + m];
#pragma unroll
            for (int m = 0; m < 4; ++m)
                *(float4*)&C[(size_t)row * 128 + cc + m * 4] =
                    make_float4(v[m * 4], v[m * 4 + 1], v[m * 4 + 2], v[m * 4 + 3]);
        }
    }
}

// ---------------------------------------------------------------------------
// KWa[n][4] = K[n][128] @ Wa[128][4] — one wave per row.
// ---------------------------------------------------------------------------
__global__ __launch_bounds__(256) void kwa_kernel(
    const float* __restrict__ K, const float* __restrict__ Wa,
    float* __restrict__ kwa, int n)
{
    const int r = (int)((blockIdx.x * blockDim.x + threadIdx.x) >> 6);
    if (r >= n) return;
    const int lane = threadIdx.x & 63;
    const float2 k = *(const float2*)&K[(size_t)r * 128 + lane * 2];
    const float4 wa0 = *(const float4*)&Wa[(lane * 2) * 4];
    const float4 wa1 = *(const float4*)&Wa[(lane * 2 + 1) * 4];
    float s0 = k.x * wa0.x + k.y * wa1.x;
    float s1 = k.x * wa0.y + k.y * wa1.y;
    float s2 = k.x * wa0.z + k.y * wa1.z;
    float s3 = k.x * wa0.w + k.y * wa1.w;
#pragma unroll
    for (int off = 32; off; off >>= 1) {
        s0 += __shfl_xor(s0, off);
        s1 += __shfl_xor(s1, off);
        s2 += __shfl_xor(s2, off);
        s3 += __shfl_xor(s3, off);
    }
    if (lane == 0)
        *(float4*)&kwa[(size_t)r * 4] = make_float4(s0, s1, s2, s3);
}

// ---------------------------------------------------------------------------
// CSR-ish bucket build: histogram -> wave-scanned cursor alloc -> scatter.
// ---------------------------------------------------------------------------
__global__ __launch_bounds__(256) void hist_kernel(
    const int* __restrict__ dst, int* __restrict__ cnt, int E)
{
    const int e = blockIdx.x * blockDim.x + threadIdx.x;
    if (e < E) atomicAdd(&cnt[dst[e]], 1);
}

__global__ __launch_bounds__(256) void alloc_kernel(
    const int* __restrict__ cnt, int* __restrict__ base,
    int* __restrict__ fill, int* __restrict__ cursor, int n)
{
    const int d = blockIdx.x * blockDim.x + threadIdx.x;
    const int lane = threadIdx.x & 63;
    int c = (d < n) ? cnt[d] : 0;
    int sc = c;                      // inclusive wave scan
#pragma unroll
    for (int off = 1; off < 64; off <<= 1) {
        int t = __shfl_up(sc, off);
        if (lane >= off) sc += t;
    }
    const int total = __shfl(sc, 63);
    int wb = 0;
    if (lane == 63) wb = atomicAdd(cursor, total);
    wb = __shfl(wb, 63);
    if (d < n) {
        const int b = wb + sc - c;   // exclusive
        base[d] = b;
        fill[d] = b;
    }
}

__global__ __launch_bounds__(256) void scatter_kernel(
    const int* __restrict__ src, const int* __restrict__ dst,
    int* __restrict__ fill, int* __restrict__ bucket_src, int E)
{
    const int e = blockIdx.x * blockDim.x + threadIdx.x;
    if (e < E) {
        const int pos = atomicAdd(&fill[dst[e]], 1);
        bucket_src[pos] = src[e];
    }
}

// ---------------------------------------------------------------------------
// Gather aggregation: one wave per dst node. No atomics, single write per row.
// ---------------------------------------------------------------------------
__global__ __launch_bounds__(256) void agg_kernel(
    const int* __restrict__ base, const int* __restrict__ cnt,
    const int* __restrict__ bucket_src,
    const float* __restrict__ K, const float* __restrict__ Q,
    const float* __restrict__ V, const float* __restrict__ kwa,
    float* __restrict__ msg, float* __restrict__ wsum, int n_dst)
{
    const int d = (int)((blockIdx.x * blockDim.x + threadIdx.x) >> 6);
    if (d >= n_dst) return;
    const int lane = threadIdx.x & 63;
    const int h = lane >> 4;
    const float inv = 0.17677669529663687f;   // 1/sqrt(32)

    const float2 q = *(const float2*)&Q[(size_t)d * 128 + lane * 2];
    const int b = base[d], c = cnt[d];

    float2 macc = make_float2(0.f, 0.f);
    float wacc = 0.f;

    for (int i = 0; i < c; ++i) {
        const int s = bucket_src[b + i];
        const float2 ek = *(const float2*)&K[(size_t)s * 128 + lane * 2];
        const float2 ev = *(const float2*)&V[(size_t)s * 128 + lane * 2];
        const float4 kw = *(const float4*)&kwa[(size_t)s * 4];

        float p = ek.x * q.x + ek.y * q.y;        // per-head dot partial
        p += __shfl_xor(p, 8);
        p += __shfl_xor(p, 4);
        p += __shfl_xor(p, 2);
        p += __shfl_xor(p, 1);
        const float d0 = __shfl(p, 0),  d1 = __shfl(p, 16);
        const float d2 = __shfl(p, 32), d3 = __shfl(p, 48);

        const float sc0 = d0 * inv + kw.x;
        const float sc1 = d1 * inv + kw.y;
        const float sc2 = d2 * inv + kw.z;
        const float sc3 = d3 * inv + kw.w;
        const float m = fmaxf(fmaxf(sc0, sc1), fmaxf(sc2, sc3));
        const float e0 = __expf(sc0 - m);
        const float e1 = __expf(sc1 - m);
        const float e2 = __expf(sc2 - m);
        const float e3 = __expf(sc3 - m);
        const float rs = 1.0f / (e0 + e1 + e2 + e3);
        const float a0 = e0 * rs, a1 = e1 * rs, a2 = e2 * rs, a3 = e3 * rs;
        const float att = (h == 0) ? a0 : (h == 1) ? a1 : (h == 2) ? a2 : a3;

        macc.x += att * ev.x;
        macc.y += att * ev.y;
        wacc += a0 + a1 + a2 + a3;
    }

    *(float2*)&msg[(size_t)d * 128 + lane * 2] = macc;
    if (lane == 0) wsum[d] = wacc;
}

// ---------------------------------------------------------------------------
extern "C" void kernel_launch(void* const* d_in, const int* in_sizes, int n_in,
                              void* d_out, int out_size, void* d_ws, size_t ws_size,
                              hipStream_t stream)
{
    const float* x_user  = (const float*)d_in[0];
    const float* x_item  = (const float*)d_in[1];
    const int*   ei_ui   = (const int*)d_in[2];
    const int*   ei_iu   = (const int*)d_in[3];
    const float* Wk_user = (const float*)d_in[4];
    const float* Wq_user = (const float*)d_in[5];
    const float* Wv_user = (const float*)d_in[6];
    const float* Wk_item = (const float*)d_in[7];
    const float* Wq_item = (const float*)d_in[8];
    const float* Wv_item = (const float*)d_in[9];
    const float* Wa_ui   = (const float*)d_in[10];
    const float* Wa_iu   = (const float*)d_in[11];
    const float* Wm_user = (const float*)d_in[12];
    const float* bm_user = (const float*)d_in[13];
    const float* Wm_item = (const float*)d_in[14];
    const float* bm_item = (const float*)d_in[15];
    const float* Wg_user = (const float*)d_in[16];
    const float* bg_user = (const float*)d_in[17];
    const float* Wg_item = (const float*)d_in[18];
    const float* bg_item = (const float*)d_in[19];
    const float* lng_user = (const float*)d_in[20];
    const float* lnb_user = (const float*)d_in[21];
    const float* lng_item = (const float*)d_in[22];
    const float* lnb_item = (const float*)d_in[23];

    const int n_user = in_sizes[0] / DIM;
    const int n_item = in_sizes[1] / DIM;
    const int E = in_sizes[2] / 2;
    const int nmax = (n_user > n_item) ? n_user : n_item;
    const size_t nf_max = (size_t)nmax * DIM;
    const size_t nf_u = (size_t)n_user * DIM;

    float* ws    = (float*)d_ws;
    float* bufK  = ws;                        // [nmax,128]
    float* bufV  = bufK + nf_max;             // [nmax,128]
    float* bufQ  = bufV + nf_max;             // [nmax,128]
    float* msg   = bufQ + nf_max;             // [nmax,128]
    float* kwa   = msg + nf_max;              // [nmax,4]
    float* wsum  = kwa + (size_t)nmax * 4;    // [nmax]
    int*   cnt   = (int*)(wsum + nmax);       // [nmax]
    int*   basep = cnt + nmax;                // [nmax]
    int*   fill  = basep + nmax;              // [nmax]
    int*   cursor = fill + nmax;              // [4]
    int*   bucket = cursor + 4;               // [E]
    float* tmp   = bufK;                      // reused after agg

    float* out_user = (float*)d_out;
    float* out_item = out_user + nf_u;

    const dim3 blk(256);
    const int grid_u = (n_user + TILE_R - 1) / TILE_R;
    const int grid_i = (n_item + TILE_R - 1) / TILE_R;
    const int grid_e = (E + 255) / 256;
    const int grid_wu = (n_user + 3) / 4;   // wave-per-row grids
    const int grid_wi = (n_item + 3) / 4;

    // ---------------- Phase A: dst = item (edges user -> item) ----------------
    gemm128<0><<<grid_u, blk, 0, stream>>>(x_user, Wk_user, nullptr, nullptr, nullptr, nullptr, nullptr, bufK, n_user);
    gemm128<0><<<grid_u, blk, 0, stream>>>(x_user, Wv_user, nullptr, nullptr, nullptr, nullptr, nullptr, bufV, n_user);
    gemm128<0><<<grid_i, blk, 0, stream>>>(x_item, Wq_item, nullptr, nullptr, nullptr, nullptr, nullptr, bufQ, n_item);
    kwa_kernel<<<grid_wu, blk, 0, stream>>>(bufK, Wa_ui, kwa, n_user);

    hipMemsetAsync(cnt, 0, (size_t)nmax * sizeof(int), stream);
    hipMemsetAsync(cursor, 0, 4 * sizeof(int), stream);
    hist_kernel<<<grid_e, blk, 0, stream>>>(ei_ui + E, cnt, E);
    alloc_kernel<<<(nmax + 255) / 256, blk, 0, stream>>>(cnt, basep, fill, cursor, n_item);
    scatter_kernel<<<grid_e, blk, 0, stream>>>(ei_ui, ei_ui + E, fill, bucket, E);

    agg_kernel<<<grid_wi, blk, 0, stream>>>(basep, cnt, bucket, bufK, bufQ, bufV, kwa, msg, wsum, n_item);

    gemm128<1><<<grid_i, blk, 0, stream>>>(msg, Wm_item, bm_item, wsum, nullptr, nullptr, nullptr, tmp, n_item);
    gemm128<2><<<grid_i, blk, 0, stream>>>(tmp, Wg_item, bg_item, nullptr, x_item, lng_item, lnb_item, out_item, n_item);

    // ---------------- Phase B: dst = user (edges item -> user) ----------------
    gemm128<0><<<grid_i, blk, 0, stream>>>(x_item, Wk_item, nullptr, nullptr, nullptr, nullptr, nullptr, bufK, n_item);
    gemm128<0><<<grid_i, blk, 0, stream>>>(x_item, Wv_item, nullptr, nullptr, nullptr, nullptr, nullptr, bufV, n_item);
    gemm128<0><<<grid_u, blk, 0, stream>>>(x_user, Wq_user, nullptr, nullptr, nullptr, nullptr, nullptr, bufQ, n_user);
    kwa_kernel<<<grid_wi, blk, 0, stream>>>(bufK, Wa_iu, kwa, n_item);

    hipMemsetAsync(cnt, 0, (size_t)nmax * sizeof(int), stream);
    hipMemsetAsync(cursor, 0, 4 * sizeof(int), stream);
    hist_kernel<<<grid_e, blk, 0, stream>>>(ei_iu + E, cnt, E);
    alloc_kernel<<<(nmax + 255) / 256, blk, 0, stream>>>(cnt, basep, fill, cursor, n_user);
    scatter_kernel<<<grid_e, blk, 0, stream>>>(ei_iu, ei_iu + E, fill, bucket, E);

    agg_kernel<<<grid_wu, blk, 0, stream>>>(basep, cnt, bucket, bufK, bufQ, bufV, kwa, msg, wsum, n_user);

    gemm128<1><<<grid_u, blk, 0, stream>>>(msg, Wm_user, bm_user, wsum, nullptr, nullptr, nullptr, tmp, n_user);
    gemm128<2><<<grid_u, blk, 0, stream>>>(tmp, Wg_user, bg_user, nullptr, x_user, lng_user, lnb_user, out_user, n_user);
}

// Round 3
// 384.368 us; speedup vs baseline: 2.7631x; 1.6365x over previous
//
#include <hip/hip_runtime.h>
#include <hip/hip_bf16.h>

#define DIM 128

typedef short s16x8 __attribute__((ext_vector_type(8)));
typedef float f32x4 __attribute__((ext_vector_type(4)));

__device__ __forceinline__ ushort f2b(float f) {
    __hip_bfloat16 h = __float2bfloat16(f);
    return *reinterpret_cast<ushort*>(&h);
}
__device__ __forceinline__ uint pk2(float a, float b) {
    return (uint)f2b(a) | ((uint)f2b(b) << 16);
}
__device__ __forceinline__ float bl(uint u) { return __uint_as_float(u << 16); }
__device__ __forceinline__ float bh(uint u) { return __uint_as_float(u & 0xffff0000u); }

// Swizzled byte address inside a [rows][128 bf16] LDS tile (256B rows).
// XOR spreads the 16 rows a wave reads across 8 distinct 16B slots (T2).
__device__ __forceinline__ int swz(int row, int kelem) {
    int b = row * 256 + kelem * 2;
    return b ^ ((row & 7) << 4);
}

__device__ __forceinline__ s16x8 read_frag(const char* lds, int row, int k0) {
    return *(const s16x8*)(lds + swz(row, k0));
}

// Build Wt[n][k] = bf16(W[k][n]) in LDS, swizzled. Coalesced row reads of W.
__device__ __forceinline__ void build_wt(const float* __restrict__ W, char* lds) {
    const int t = threadIdx.x;
    const int n = t & 127;
    const int kbase = (t >> 7) * 64;
#pragma unroll
    for (int c = 0; c < 8; ++c) {
        const int k0 = kbase + c * 8;
        float v[8];
#pragma unroll
        for (int j = 0; j < 8; ++j) v[j] = W[(size_t)(k0 + j) * 128 + n];
        uint4 u;
        u.x = pk2(v[0], v[1]); u.y = pk2(v[2], v[3]);
        u.z = pk2(v[4], v[5]); u.w = pk2(v[6], v[7]);
        *(uint4*)(lds + swz(n, k0)) = u;
    }
}

// Stage a 64x128 A-tile into swizzled LDS. fp32 source (convert) / bf16 source (copy).
__device__ __forceinline__ void stage_f32(const float* __restrict__ src, int r0, int N, char* lds) {
    const int t = threadIdx.x;
    const int r = t >> 2;
    const int k0 = (t & 3) * 32;
    const int row = r0 + r;
#pragma unroll
    for (int c = 0; c < 4; ++c) {
        uint4 u = make_uint4(0, 0, 0, 0);
        if (row < N) {
            const float4 f0 = *(const float4*)&src[(size_t)row * 128 + k0 + c * 8];
            const float4 f1 = *(const float4*)&src[(size_t)row * 128 + k0 + c * 8 + 4];
            u.x = pk2(f0.x, f0.y); u.y = pk2(f0.z, f0.w);
            u.z = pk2(f1.x, f1.y); u.w = pk2(f1.z, f1.w);
        }
        *(uint4*)(lds + swz(r, k0 + c * 8)) = u;
    }
}

__device__ __forceinline__ void stage_b16(const ushort* __restrict__ src, int r0, int N, char* lds) {
    const int t = threadIdx.x;
    const int r = t >> 2;
    const int k0 = (t & 3) * 32;
    const int row = r0 + r;
#pragma unroll
    for (int c = 0; c < 4; ++c) {
        uint4 u = make_uint4(0, 0, 0, 0);
        if (row < N) u = *(const uint4*)&src[(size_t)row * 128 + k0 + c * 8];
        *(uint4*)(lds + swz(r, k0 + c * 8)) = u;
    }
}

// One 16-row-stripe x 32-col product (wave's 2 col-tiles), bf16 output.
__device__ __forceinline__ void compute_store(
    const s16x8 af[4], const s16x8 b[2][4], ushort* __restrict__ out,
    int r0, int rt, int w, int lr, int lg, int N)
{
#pragma unroll
    for (int ct = 0; ct < 2; ++ct) {
        f32x4 acc = {0.f, 0.f, 0.f, 0.f};
#pragma unroll
        for (int kb = 0; kb < 4; ++kb)
            acc = __builtin_amdgcn_mfma_f32_16x16x32_bf16(af[kb], b[ct][kb], acc, 0, 0, 0);
        const int col = w * 32 + ct * 16 + lr;
        const int rbase = r0 + rt * 16 + 4 * lg;
#pragma unroll
        for (int j = 0; j < 4; ++j)
            if (rbase + j < N) out[(size_t)(rbase + j) * 128 + col] = f2b(acc[j]);
    }
}

// ---------------------------------------------------------------------------
// proj: K/Q/V = x @ {Wk,Wq,Wv}, bf16 out. B-frags persistent in registers.
// ---------------------------------------------------------------------------
__global__ __launch_bounds__(256) void proj_kernel(
    const float* __restrict__ x,
    const float* __restrict__ Wk, const float* __restrict__ Wq, const float* __restrict__ Wv,
    ushort* __restrict__ K, ushort* __restrict__ Q, ushort* __restrict__ V, int N)
{
    __shared__ char wt[32768];
    __shared__ char at[16384];
    const int t = threadIdx.x, w = t >> 6, l = t & 63;
    const int lr = l & 15, lg = l >> 4;

    s16x8 bK[2][4], bQ[2][4], bV[2][4];

    build_wt(Wk, wt);
    __syncthreads();
#pragma unroll
    for (int ct = 0; ct < 2; ++ct)
#pragma unroll
        for (int kb = 0; kb < 4; ++kb)
            bK[ct][kb] = read_frag(wt, w * 32 + ct * 16 + lr, kb * 32 + 8 * lg);
    __syncthreads();
    build_wt(Wq, wt);
    __syncthreads();
#pragma unroll
    for (int ct = 0; ct < 2; ++ct)
#pragma unroll
        for (int kb = 0; kb < 4; ++kb)
            bQ[ct][kb] = read_frag(wt, w * 32 + ct * 16 + lr, kb * 32 + 8 * lg);
    __syncthreads();
    build_wt(Wv, wt);
    __syncthreads();
#pragma unroll
    for (int ct = 0; ct < 2; ++ct)
#pragma unroll
        for (int kb = 0; kb < 4; ++kb)
            bV[ct][kb] = read_frag(wt, w * 32 + ct * 16 + lr, kb * 32 + 8 * lg);

    const int ntiles = (N + 63) >> 6;
    for (int tile = blockIdx.x; tile < ntiles; tile += gridDim.x) {
        const int r0 = tile << 6;
        __syncthreads();
        stage_f32(x, r0, N, at);
        __syncthreads();
#pragma unroll
        for (int rt = 0; rt < 4; ++rt) {
            s16x8 af[4];
#pragma unroll
            for (int kb = 0; kb < 4; ++kb)
                af[kb] = read_frag(at, rt * 16 + lr, kb * 32 + 8 * lg);
            compute_store(af, bK, K, r0, rt, w, lr, lg, N);
            compute_store(af, bQ, Q, r0, rt, w, lr, lg, N);
            compute_store(af, bV, V, r0, rt, w, lr, lg, N);
        }
    }
}

// ---------------------------------------------------------------------------
// mode1: tmp = (msg @ Wm) * (1/max(wsum,1e-8)) + bm   (bf16 in/out)
// ---------------------------------------------------------------------------
__global__ __launch_bounds__(256) void mode1_kernel(
    const ushort* __restrict__ A, const float* __restrict__ Wm, const float* __restrict__ bm,
    const float* __restrict__ wsum, ushort* __restrict__ out, int N)
{
    __shared__ char wt[32768];
    __shared__ char at[16384];
    const int t = threadIdx.x, w = t >> 6, l = t & 63;
    const int lr = l & 15, lg = l >> 4;

    s16x8 B[2][4];
    build_wt(Wm, wt);
    __syncthreads();
#pragma unroll
    for (int ct = 0; ct < 2; ++ct)
#pragma unroll
        for (int kb = 0; kb < 4; ++kb)
            B[ct][kb] = read_frag(wt, w * 32 + ct * 16 + lr, kb * 32 + 8 * lg);
    const float bm0 = bm[w * 32 + lr], bm1 = bm[w * 32 + 16 + lr];

    const int ntiles = (N + 63) >> 6;
    for (int tile = blockIdx.x; tile < ntiles; tile += gridDim.x) {
        const int r0 = tile << 6;
        __syncthreads();
        stage_b16(A, r0, N, at);
        __syncthreads();
#pragma unroll
        for (int rt = 0; rt < 4; ++rt) {
            s16x8 af[4];
#pragma unroll
            for (int kb = 0; kb < 4; ++kb)
                af[kb] = read_frag(at, rt * 16 + lr, kb * 32 + 8 * lg);
            const int rbase = r0 + rt * 16 + 4 * lg;
            float rs[4];
#pragma unroll
            for (int j = 0; j < 4; ++j)
                rs[j] = (rbase + j < N) ? 1.0f / fmaxf(wsum[rbase + j], 1e-8f) : 0.f;
#pragma unroll
            for (int ct = 0; ct < 2; ++ct) {
                f32x4 acc = {0.f, 0.f, 0.f, 0.f};
#pragma unroll
                for (int kb = 0; kb < 4; ++kb)
                    acc = __builtin_amdgcn_mfma_f32_16x16x32_bf16(af[kb], B[ct][kb], acc, 0, 0, 0);
                const float bb = ct ? bm1 : bm0;
                const int col = w * 32 + ct * 16 + lr;
#pragma unroll
                for (int j = 0; j < 4; ++j)
                    if (rbase + j < N)
                        out[(size_t)(rbase + j) * 128 + col] = f2b(acc[j] * rs[j] + bb);
            }
        }
    }
}

// ---------------------------------------------------------------------------
// mode2: out = LayerNorm(tmp @ Wg + bg + resid) * gamma + beta   (fp32 out)
// ---------------------------------------------------------------------------
__global__ __launch_bounds__(256) void mode2_kernel(
    const ushort* __restrict__ A, const float* __restrict__ Wg, const float* __restrict__ bg,
    const float* __restrict__ resid, const float* __restrict__ gamma, const float* __restrict__ beta,
    float* __restrict__ out, int N)
{
    __shared__ char wt[32768];
    __shared__ char at[16384];
    __shared__ float2 part[4][64];
    __shared__ float2 lnp[64];
    const int t = threadIdx.x, w = t >> 6, l = t & 63;
    const int lr = l & 15, lg = l >> 4;

    s16x8 B[2][4];
    build_wt(Wg, wt);
    __syncthreads();
#pragma unroll
    for (int ct = 0; ct < 2; ++ct)
#pragma unroll
        for (int kb = 0; kb < 4; ++kb)
            B[ct][kb] = read_frag(wt, w * 32 + ct * 16 + lr, kb * 32 + 8 * lg);

    const int col0 = w * 32 + lr, col1 = col0 + 16;
    const float bg0 = bg[col0], bg1 = bg[col1];
    const float g0 = gamma[col0], g1 = gamma[col1];
    const float be0 = beta[col0], be1 = beta[col1];

    const int ntiles = (N + 63) >> 6;
    for (int tile = blockIdx.x; tile < ntiles; tile += gridDim.x) {
        const int r0 = tile << 6;
        __syncthreads();
        stage_b16(A, r0, N, at);
        __syncthreads();

        float v[4][2][4];
#pragma unroll
        for (int rt = 0; rt < 4; ++rt) {
            s16x8 af[4];
#pragma unroll
            for (int kb = 0; kb < 4; ++kb)
                af[kb] = read_frag(at, rt * 16 + lr, kb * 32 + 8 * lg);
            const int rbase = r0 + rt * 16 + 4 * lg;
#pragma unroll
            for (int ct = 0; ct < 2; ++ct) {
                f32x4 acc = {0.f, 0.f, 0.f, 0.f};
#pragma unroll
                for (int kb = 0; kb < 4; ++kb)
                    acc = __builtin_amdgcn_mfma_f32_16x16x32_bf16(af[kb], B[ct][kb], acc, 0, 0, 0);
                const int col = ct ? col1 : col0;
                const float bgc = ct ? bg1 : bg0;
#pragma unroll
                for (int j = 0; j < 4; ++j) {
                    const float rv = (rbase + j < N) ? resid[(size_t)(rbase + j) * 128 + col] : 0.f;
                    v[rt][ct][j] = acc[j] + bgc + rv;
                }
            }
        }
        // per-row partial sums over this wave's 32 cols -> LDS
#pragma unroll
        for (int rt = 0; rt < 4; ++rt)
#pragma unroll
            for (int j = 0; j < 4; ++j) {
                float s = v[rt][0][j] + v[rt][1][j];
                float q = v[rt][0][j] * v[rt][0][j] + v[rt][1][j] * v[rt][1][j];
                s += __shfl_xor(s, 8); q += __shfl_xor(q, 8);
                s += __shfl_xor(s, 4); q += __shfl_xor(q, 4);
                s += __shfl_xor(s, 2); q += __shfl_xor(q, 2);
                s += __shfl_xor(s, 1); q += __shfl_xor(q, 1);
                if (lr == 0) part[w][rt * 16 + 4 * lg + j] = make_float2(s, q);
            }
        __syncthreads();
        if (t < 64) {
            const float S = part[0][t].x + part[1][t].x + part[2][t].x + part[3][t].x;
            const float Qq = part[0][t].y + part[1][t].y + part[2][t].y + part[3][t].y;
            const float mu = S * (1.f / 128.f);
            const float var = Qq * (1.f / 128.f) - mu * mu;
            lnp[t] = make_float2(mu, rsqrtf(var + 1e-5f));
        }
        __syncthreads();
#pragma unroll
        for (int rt = 0; rt < 4; ++rt) {
            const int rbase = r0 + rt * 16 + 4 * lg;
#pragma unroll
            for (int j = 0; j < 4; ++j) {
                const float2 mp = lnp[rt * 16 + 4 * lg + j];
                if (rbase + j < N) {
                    out[(size_t)(rbase + j) * 128 + col0] = (v[rt][0][j] - mp.x) * mp.y * g0 + be0;
                    out[(size_t)(rbase + j) * 128 + col1] = (v[rt][1][j] - mp.x) * mp.y * g1 + be1;
                }
            }
        }
    }
}

// ---------------------------------------------------------------------------
// KWa[n][4] = K[n][128] @ Wa[128][4] — one wave per row, bf16 K.
// ---------------------------------------------------------------------------
__global__ __launch_bounds__(256) void kwa_kernel(
    const ushort* __restrict__ K, const float* __restrict__ Wa,
    float* __restrict__ kwa, int n)
{
    const int r = (int)((blockIdx.x * blockDim.x + threadIdx.x) >> 6);
    if (r >= n) return;
    const int l = threadIdx.x & 63;
    const uint ku = *(const uint*)&K[(size_t)r * 128 + 2 * l];
    const float kx = bl(ku), ky = bh(ku);
    const float4 wa0 = *(const float4*)&Wa[(2 * l) * 4];
    const float4 wa1 = *(const float4*)&Wa[(2 * l + 1) * 4];
    float s0 = kx * wa0.x + ky * wa1.x;
    float s1 = kx * wa0.y + ky * wa1.y;
    float s2 = kx * wa0.z + ky * wa1.z;
    float s3 = kx * wa0.w + ky * wa1.w;
#pragma unroll
    for (int off = 32; off; off >>= 1) {
        s0 += __shfl_xor(s0, off);
        s1 += __shfl_xor(s1, off);
        s2 += __shfl_xor(s2, off);
        s3 += __shfl_xor(s3, off);
    }
    if (l == 0) *(float4*)&kwa[(size_t)r * 4] = make_float4(s0, s1, s2, s3);
}

// ---------------------------------------------------------------------------
// Bucket build (unchanged from round 2)
// ---------------------------------------------------------------------------
__global__ __launch_bounds__(256) void hist_kernel(
    const int* __restrict__ dst, int* __restrict__ cnt, int E)
{
    const int e = blockIdx.x * blockDim.x + threadIdx.x;
    if (e < E) atomicAdd(&cnt[dst[e]], 1);
}

__global__ __launch_bounds__(256) void alloc_kernel(
    const int* __restrict__ cnt, int* __restrict__ base,
    int* __restrict__ fill, int* __restrict__ cursor, int n)
{
    const int d = blockIdx.x * blockDim.x + threadIdx.x;
    const int lane = threadIdx.x & 63;
    int c = (d < n) ? cnt[d] : 0;
    int sc = c;
#pragma unroll
    for (int off = 1; off < 64; off <<= 1) {
        int t = __shfl_up(sc, off);
        if (lane >= off) sc += t;
    }
    const int total = __shfl(sc, 63);
    int wb = 0;
    if (lane == 63) wb = atomicAdd(cursor, total);
    wb = __shfl(wb, 63);
    if (d < n) {
        const int b = wb + sc - c;
        base[d] = b;
        fill[d] = b;
    }
}

__global__ __launch_bounds__(256) void scatter_kernel(
    const int* __restrict__ src, const int* __restrict__ dst,
    int* __restrict__ fill, int* __restrict__ bucket_src, int E)
{
    const int e = blockIdx.x * blockDim.x + threadIdx.x;
    if (e < E) {
        const int pos = atomicAdd(&fill[dst[e]], 1);
        bucket_src[pos] = src[e];
    }
}

// ---------------------------------------------------------------------------
// Gather aggregation, bf16 K/Q/V. wsum = degree (softmax over heads sums to 1).
// ---------------------------------------------------------------------------
__global__ __launch_bounds__(256) void agg_kernel(
    const int* __restrict__ base, const int* __restrict__ cnt, const int* __restrict__ bsrc,
    const ushort* __restrict__ K, const ushort* __restrict__ Q, const ushort* __restrict__ V,
    const float* __restrict__ kwa, ushort* __restrict__ msg, float* __restrict__ wsum, int n)
{
    const int d = (int)((blockIdx.x * blockDim.x + threadIdx.x) >> 6);
    if (d >= n) return;
    const int l = threadIdx.x & 63;
    const int h = l >> 4;
    const float inv = 0.17677669529663687f;   // 1/sqrt(32)
    const uint qu = *(const uint*)&Q[(size_t)d * 128 + 2 * l];
    const float qx = bl(qu), qy = bh(qu);
    const int b = base[d], c = cnt[d];
    float mx = 0.f, my = 0.f;

    for (int i = 0; i < c; ++i) {
        const int s = bsrc[b + i];
        const uint ku = *(const uint*)&K[(size_t)s * 128 + 2 * l];
        const uint vu = *(const uint*)&V[(size_t)s * 128 + 2 * l];
        const float kw = kwa[(size_t)s * 4 + h];
        float p = bl(ku) * qx + bh(ku) * qy;
        p += __shfl_xor(p, 8);
        p += __shfl_xor(p, 4);
        p += __shfl_xor(p, 2);
        p += __shfl_xor(p, 1);
        const float e = __expf(p * inv + kw);
        float es = e + __shfl_xor(e, 16);
        es += __shfl_xor(es, 32);
        const float att = __fdividef(e, es);
        mx += att * bl(vu);
        my += att * bh(vu);
    }
    *(uint*)&msg[(size_t)d * 128 + 2 * l] = pk2(mx, my);
    if (l == 0) wsum[d] = (float)c;
}

// ---------------------------------------------------------------------------
extern "C" void kernel_launch(void* const* d_in, const int* in_sizes, int n_in,
                              void* d_out, int out_size, void* d_ws, size_t ws_size,
                              hipStream_t stream)
{
    const float* x_user  = (const float*)d_in[0];
    const float* x_item  = (const float*)d_in[1];
    const int*   ei_ui   = (const int*)d_in[2];
    const int*   ei_iu   = (const int*)d_in[3];
    const float* Wk_user = (const float*)d_in[4];
    const float* Wq_user = (const float*)d_in[5];
    const float* Wv_user = (const float*)d_in[6];
    const float* Wk_item = (const float*)d_in[7];
    const float* Wq_item = (const float*)d_in[8];
    const float* Wv_item = (const float*)d_in[9];
    const float* Wa_ui   = (const float*)d_in[10];
    const float* Wa_iu   = (const float*)d_in[11];
    const float* Wm_user = (const float*)d_in[12];
    const float* bm_user = (const float*)d_in[13];
    const float* Wm_item = (const float*)d_in[14];
    const float* bm_item = (const float*)d_in[15];
    const float* Wg_user = (const float*)d_in[16];
    const float* bg_user = (const float*)d_in[17];
    const float* Wg_item = (const float*)d_in[18];
    const float* bg_item = (const float*)d_in[19];
    const float* lng_user = (const float*)d_in[20];
    const float* lnb_user = (const float*)d_in[21];
    const float* lng_item = (const float*)d_in[22];
    const float* lnb_item = (const float*)d_in[23];

    const int n_user = in_sizes[0] / DIM;
    const int n_item = in_sizes[1] / DIM;
    const int E = in_sizes[2] / 2;
    const int nmax = (n_user > n_item) ? n_user : n_item;
    const size_t nf = (size_t)nmax * DIM;

    ushort* Ku = (ushort*)d_ws;
    ushort* Qu = Ku + nf;
    ushort* Vu = Qu + nf;
    ushort* Ki = Vu + nf;
    ushort* Qi = Ki + nf;
    ushort* Vi = Qi + nf;
    ushort* msg = Vi + nf;
    float* kwa_u = (float*)(msg + nf);
    float* kwa_i = kwa_u + (size_t)nmax * 4;
    float* wsum = kwa_i + (size_t)nmax * 4;
    int* cnt = (int*)(wsum + nmax);
    int* basep = cnt + nmax;
    int* fill = basep + nmax;
    int* cursor = fill + nmax;
    int* bucket = cursor + 4;
    ushort* tmpb = Ku;   // Ku dead after phase-A agg; reuse as tmp

    float* out_user = (float*)d_out;
    float* out_item = out_user + (size_t)n_user * DIM;

    const dim3 blk(256);
    const int ntu = (n_user + 63) / 64, nti = (n_item + 63) / 64;
    const int gpu_ = (ntu < 768) ? ntu : 768;
    const int gpi  = (nti < 768) ? nti : 768;
    const int grid_e = (E + 255) / 256;

    proj_kernel<<<gpu_, blk, 0, stream>>>(x_user, Wk_user, Wq_user, Wv_user, Ku, Qu, Vu, n_user);
    proj_kernel<<<gpi, blk, 0, stream>>>(x_item, Wk_item, Wq_item, Wv_item, Ki, Qi, Vi, n_item);
    kwa_kernel<<<(n_user + 3) / 4, blk, 0, stream>>>(Ku, Wa_ui, kwa_u, n_user);
    kwa_kernel<<<(n_item + 3) / 4, blk, 0, stream>>>(Ki, Wa_iu, kwa_i, n_item);

    // ---- Phase A: dst = item (edges user -> item) ----
    hipMemsetAsync(cnt, 0, ((size_t)nmax * 3 + 4) * sizeof(int), stream);
    hist_kernel<<<grid_e, blk, 0, stream>>>(ei_ui + E, cnt, E);
    alloc_kernel<<<(n_item + 255) / 256, blk, 0, stream>>>(cnt, basep, fill, cursor, n_item);
    scatter_kernel<<<grid_e, blk, 0, stream>>>(ei_ui, ei_ui + E, fill, bucket, E);
    agg_kernel<<<(n_item + 3) / 4, blk, 0, stream>>>(basep, cnt, bucket, Ku, Qi, Vu, kwa_u, msg, wsum, n_item);
    mode1_kernel<<<gpi, blk, 0, stream>>>(msg, Wm_item, bm_item, wsum, tmpb, n_item);
    mode2_kernel<<<gpi, blk, 0, stream>>>(tmpb, Wg_item, bg_item, x_item, lng_item, lnb_item, out_item, n_item);

    // ---- Phase B: dst = user (edges item -> user) ----
    hipMemsetAsync(cnt, 0, ((size_t)nmax * 3 + 4) * sizeof(int), stream);
    hist_kernel<<<grid_e, blk, 0, stream>>>(ei_iu + E, cnt, E);
    alloc_kernel<<<(n_user + 255) / 256, blk, 0, stream>>>(cnt, basep, fill, cursor, n_user);
    scatter_kernel<<<grid_e, blk, 0, stream>>>(ei_iu, ei_iu + E, fill, bucket, E);
    agg_kernel<<<(n_user + 3) / 4, blk, 0, stream>>>(basep, cnt, bucket, Ki, Qu, Vi, kwa_i, msg, wsum, n_user);
    mode1_kernel<<<gpu_, blk, 0, stream>>>(msg, Wm_user, bm_user, wsum, tmpb, n_user);
    mode2_kernel<<<gpu_, blk, 0, stream>>>(tmpb, Wg_user, bg_user, x_user, lng_user, lnb_user, out_user, n_user);
}

// Round 4
// 360.068 us; speedup vs baseline: 2.9496x; 1.0675x over previous
//
#include <hip/hip_runtime.h>
#include <hip/hip_bf16.h>

#define DIM 128

typedef short s16x8 __attribute__((ext_vector_type(8)));
typedef float f32x4 __attribute__((ext_vector_type(4)));

__device__ __forceinline__ ushort f2b(float f) {
    __hip_bfloat16 h = __float2bfloat16(f);
    return *reinterpret_cast<ushort*>(&h);
}
__device__ __forceinline__ uint pk2(float a, float b) {
    return (uint)f2b(a) | ((uint)f2b(b) << 16);
}
__device__ __forceinline__ float bl(uint u) { return __uint_as_float(u << 16); }
__device__ __forceinline__ float bh(uint u) { return __uint_as_float(u & 0xffff0000u); }

// Swizzled byte address inside a [rows][128 bf16] LDS tile (256B rows).
__device__ __forceinline__ int swz(int row, int kelem) {
    int b = row * 256 + kelem * 2;
    return b ^ ((row & 7) << 4);
}
__device__ __forceinline__ s16x8 read_frag(const char* lds, int row, int k0) {
    return *(const s16x8*)(lds + swz(row, k0));
}

// Wt[n][k] = bf16(W[k][n]) in LDS, swizzled.
__device__ __forceinline__ void build_wt(const float* __restrict__ W, char* lds) {
    const int t = threadIdx.x;
    const int n = t & 127;
    const int kbase = (t >> 7) * 64;
#pragma unroll
    for (int c = 0; c < 8; ++c) {
        const int k0 = kbase + c * 8;
        float v[8];
#pragma unroll
        for (int j = 0; j < 8; ++j) v[j] = W[(size_t)(k0 + j) * 128 + n];
        uint4 u;
        u.x = pk2(v[0], v[1]); u.y = pk2(v[2], v[3]);
        u.z = pk2(v[4], v[5]); u.w = pk2(v[6], v[7]);
        *(uint4*)(lds + swz(n, k0)) = u;
    }
}

__device__ __forceinline__ void stage_f32(const float* __restrict__ src, int r0, int N, char* lds) {
    const int t = threadIdx.x;
    const int r = t >> 2;
    const int k0 = (t & 3) * 32;
    const int row = r0 + r;
#pragma unroll
    for (int c = 0; c < 4; ++c) {
        uint4 u = make_uint4(0, 0, 0, 0);
        if (row < N) {
            const float4 f0 = *(const float4*)&src[(size_t)row * 128 + k0 + c * 8];
            const float4 f1 = *(const float4*)&src[(size_t)row * 128 + k0 + c * 8 + 4];
            u.x = pk2(f0.x, f0.y); u.y = pk2(f0.z, f0.w);
            u.z = pk2(f1.x, f1.y); u.w = pk2(f1.z, f1.w);
        }
        *(uint4*)(lds + swz(r, k0 + c * 8)) = u;
    }
}

__device__ __forceinline__ void stage_b16(const ushort* __restrict__ src, int r0, int N, char* lds) {
    const int t = threadIdx.x;
    const int r = t >> 2;
    const int k0 = (t & 3) * 32;
    const int row = r0 + r;
#pragma unroll
    for (int c = 0; c < 4; ++c) {
        uint4 u = make_uint4(0, 0, 0, 0);
        if (row < N) u = *(const uint4*)&src[(size_t)row * 128 + k0 + c * 8];
        *(uint4*)(lds + swz(r, k0 + c * 8)) = u;
    }
}

__device__ __forceinline__ void compute_store(
    const s16x8 af[4], const s16x8 b[2][4], ushort* __restrict__ out,
    int r0, int rt, int w, int lr, int lg, int N)
{
#pragma unroll
    for (int ct = 0; ct < 2; ++ct) {
        f32x4 acc = {0.f, 0.f, 0.f, 0.f};
#pragma unroll
        for (int kb = 0; kb < 4; ++kb)
            acc = __builtin_amdgcn_mfma_f32_16x16x32_bf16(af[kb], b[ct][kb], acc, 0, 0, 0);
        const int col = w * 32 + ct * 16 + lr;
        const int rbase = r0 + rt * 16 + 4 * lg;
#pragma unroll
        for (int j = 0; j < 4; ++j)
            if (rbase + j < N) out[(size_t)(rbase + j) * 128 + col] = f2b(acc[j]);
    }
}

// ---------------------------------------------------------------------------
// proj: K/Q/V = x @ {Wk,Wq,Wv} (bf16 out) + fused kwa = (x@Wk) @ Wa (fp32).
// ---------------------------------------------------------------------------
__global__ __launch_bounds__(256) void proj_kernel(
    const float* __restrict__ x,
    const float* __restrict__ Wk, const float* __restrict__ Wq, const float* __restrict__ Wv,
    const float* __restrict__ Wa,
    ushort* __restrict__ K, ushort* __restrict__ Q, ushort* __restrict__ V,
    float* __restrict__ kwa, int N)
{
    __shared__ char wt[32768];
    __shared__ char at[16384];
    __shared__ float kwp[4][64][4];
    const int t = threadIdx.x, w = t >> 6, l = t & 63;
    const int lr = l & 15, lg = l >> 4;

    s16x8 bK[2][4], bQ[2][4], bV[2][4];

    build_wt(Wk, wt);
    __syncthreads();
#pragma unroll
    for (int ct = 0; ct < 2; ++ct)
#pragma unroll
        for (int kb = 0; kb < 4; ++kb)
            bK[ct][kb] = read_frag(wt, w * 32 + ct * 16 + lr, kb * 32 + 8 * lg);
    __syncthreads();
    build_wt(Wq, wt);
    __syncthreads();
#pragma unroll
    for (int ct = 0; ct < 2; ++ct)
#pragma unroll
        for (int kb = 0; kb < 4; ++kb)
            bQ[ct][kb] = read_frag(wt, w * 32 + ct * 16 + lr, kb * 32 + 8 * lg);
    __syncthreads();
    build_wt(Wv, wt);
    __syncthreads();
#pragma unroll
    for (int ct = 0; ct < 2; ++ct)
#pragma unroll
        for (int kb = 0; kb < 4; ++kb)
            bV[ct][kb] = read_frag(wt, w * 32 + ct * 16 + lr, kb * 32 + 8 * lg);

    const int col0 = w * 32 + lr, col1 = col0 + 16;
    const float4 waA = *(const float4*)&Wa[col0 * 4];
    const float4 waB = *(const float4*)&Wa[col1 * 4];

    const int ntiles = (N + 63) >> 6;
    for (int tile = blockIdx.x; tile < ntiles; tile += gridDim.x) {
        const int r0 = tile << 6;
        __syncthreads();
        stage_f32(x, r0, N, at);
        __syncthreads();
#pragma unroll
        for (int rt = 0; rt < 4; ++rt) {
            s16x8 af[4];
#pragma unroll
            for (int kb = 0; kb < 4; ++kb)
                af[kb] = read_frag(at, rt * 16 + lr, kb * 32 + 8 * lg);
            const int rbase = r0 + rt * 16 + 4 * lg;

            // K with retained fp32 accumulators (feeds kwa)
            f32x4 aK[2];
#pragma unroll
            for (int ct = 0; ct < 2; ++ct) {
                aK[ct] = (f32x4){0.f, 0.f, 0.f, 0.f};
#pragma unroll
                for (int kb = 0; kb < 4; ++kb)
                    aK[ct] = __builtin_amdgcn_mfma_f32_16x16x32_bf16(af[kb], bK[ct][kb], aK[ct], 0, 0, 0);
            }
#pragma unroll
            for (int ct = 0; ct < 2; ++ct) {
                const int col = ct ? col1 : col0;
#pragma unroll
                for (int j = 0; j < 4; ++j)
                    if (rbase + j < N) K[(size_t)(rbase + j) * 128 + col] = f2b(aK[ct][j]);
            }
            // kwa partials: this wave's 32 cols contribution, reduce over lr
#pragma unroll
            for (int j = 0; j < 4; ++j) {
                float p0 = aK[0][j] * waA.x + aK[1][j] * waB.x;
                float p1 = aK[0][j] * waA.y + aK[1][j] * waB.y;
                float p2 = aK[0][j] * waA.z + aK[1][j] * waB.z;
                float p3 = aK[0][j] * waA.w + aK[1][j] * waB.w;
#pragma unroll
                for (int off = 8; off; off >>= 1) {
                    p0 += __shfl_xor(p0, off);
                    p1 += __shfl_xor(p1, off);
                    p2 += __shfl_xor(p2, off);
                    p3 += __shfl_xor(p3, off);
                }
                if (lr == 0) {
                    kwp[w][rt * 16 + 4 * lg + j][0] = p0;
                    kwp[w][rt * 16 + 4 * lg + j][1] = p1;
                    kwp[w][rt * 16 + 4 * lg + j][2] = p2;
                    kwp[w][rt * 16 + 4 * lg + j][3] = p3;
                }
            }
            compute_store(af, bQ, Q, r0, rt, w, lr, lg, N);
            compute_store(af, bV, V, r0, rt, w, lr, lg, N);
        }
        __syncthreads();
        if (t < 64 && r0 + t < N) {
            const float s0 = kwp[0][t][0] + kwp[1][t][0] + kwp[2][t][0] + kwp[3][t][0];
            const float s1 = kwp[0][t][1] + kwp[1][t][1] + kwp[2][t][1] + kwp[3][t][1];
            const float s2 = kwp[0][t][2] + kwp[1][t][2] + kwp[2][t][2] + kwp[3][t][2];
            const float s3 = kwp[0][t][3] + kwp[1][t][3] + kwp[2][t][3] + kwp[3][t][3];
            *(float4*)&kwa[(size_t)(r0 + t) * 4] = make_float4(s0, s1, s2, s3);
        }
    }
}

// ---------------------------------------------------------------------------
// post: out = LN( ((msg@Wm)*rs + bm) @ Wg + bg + resid ) * gamma + beta
// tmp tile kept in LDS (in-place, stripe-wise). rs = 1/max(degree,1e-8).
// ---------------------------------------------------------------------------
__global__ __launch_bounds__(256) void post_kernel(
    const ushort* __restrict__ A, const int* __restrict__ deg,
    const float* __restrict__ Wm, const float* __restrict__ bm,
    const float* __restrict__ Wg, const float* __restrict__ bg,
    const float* __restrict__ resid, const float* __restrict__ gamma,
    const float* __restrict__ beta, float* __restrict__ out, int N)
{
    __shared__ char wt[32768];
    __shared__ char at[16384];
    __shared__ float2 part[4][64];
    __shared__ float2 lnp[64];
    const int t = threadIdx.x, w = t >> 6, l = t & 63;
    const int lr = l & 15, lg = l >> 4;

    s16x8 B1[2][4], B2[2][4];
    build_wt(Wm, wt);
    __syncthreads();
#pragma unroll
    for (int ct = 0; ct < 2; ++ct)
#pragma unroll
        for (int kb = 0; kb < 4; ++kb)
            B1[ct][kb] = read_frag(wt, w * 32 + ct * 16 + lr, kb * 32 + 8 * lg);
    __syncthreads();
    build_wt(Wg, wt);
    __syncthreads();
#pragma unroll
    for (int ct = 0; ct < 2; ++ct)
#pragma unroll
        for (int kb = 0; kb < 4; ++kb)
            B2[ct][kb] = read_frag(wt, w * 32 + ct * 16 + lr, kb * 32 + 8 * lg);

    const int col0 = w * 32 + lr, col1 = col0 + 16;
    const float bm0 = bm[col0], bm1 = bm[col1];
    const float bg0 = bg[col0], bg1 = bg[col1];
    const float g0 = gamma[col0], g1 = gamma[col1];
    const float be0 = beta[col0], be1 = beta[col1];

    const int ntiles = (N + 63) >> 6;
    for (int tile = blockIdx.x; tile < ntiles; tile += gridDim.x) {
        const int r0 = tile << 6;
        __syncthreads();
        stage_b16(A, r0, N, at);
        __syncthreads();

        // Stage 1: tmp = A@Wm * rs + bm, written back into `at` stripe-wise.
#pragma unroll
        for (int rt = 0; rt < 4; ++rt) {
            s16x8 af[4];
#pragma unroll
            for (int kb = 0; kb < 4; ++kb)
                af[kb] = read_frag(at, rt * 16 + lr, kb * 32 + 8 * lg);
            __syncthreads();   // all waves read stripe rt before overwrite
            const int rbase = r0 + rt * 16 + 4 * lg;
            float rs[4];
#pragma unroll
            for (int j = 0; j < 4; ++j)
                rs[j] = (rbase + j < N) ? 1.0f / fmaxf((float)deg[rbase + j], 1e-8f) : 0.f;
#pragma unroll
            for (int ct = 0; ct < 2; ++ct) {
                f32x4 acc = {0.f, 0.f, 0.f, 0.f};
#pragma unroll
                for (int kb = 0; kb < 4; ++kb)
                    acc = __builtin_amdgcn_mfma_f32_16x16x32_bf16(af[kb], B1[ct][kb], acc, 0, 0, 0);
                const float bb = ct ? bm1 : bm0;
                const int col = ct ? col1 : col0;
#pragma unroll
                for (int j = 0; j < 4; ++j)
                    *(ushort*)(at + swz(rt * 16 + 4 * lg + j, col)) = f2b(acc[j] * rs[j] + bb);
            }
        }
        __syncthreads();

        // Stage 2: v = tmp@Wg + bg + resid
        float v[4][2][4];
#pragma unroll
        for (int rt = 0; rt < 4; ++rt) {
            s16x8 af[4];
#pragma unroll
            for (int kb = 0; kb < 4; ++kb)
                af[kb] = read_frag(at, rt * 16 + lr, kb * 32 + 8 * lg);
            const int rbase = r0 + rt * 16 + 4 * lg;
#pragma unroll
            for (int ct = 0; ct < 2; ++ct) {
                f32x4 acc = {0.f, 0.f, 0.f, 0.f};
#pragma unroll
                for (int kb = 0; kb < 4; ++kb)
                    acc = __builtin_amdgcn_mfma_f32_16x16x32_bf16(af[kb], B2[ct][kb], acc, 0, 0, 0);
                const int col = ct ? col1 : col0;
                const float bgc = ct ? bg1 : bg0;
#pragma unroll
                for (int j = 0; j < 4; ++j) {
                    const float rv = (rbase + j < N) ? resid[(size_t)(rbase + j) * 128 + col] : 0.f;
                    v[rt][ct][j] = acc[j] + bgc + rv;
                }
            }
        }
        // LayerNorm
#pragma unroll
        for (int rt = 0; rt < 4; ++rt)
#pragma unroll
            for (int j = 0; j < 4; ++j) {
                float s = v[rt][0][j] + v[rt][1][j];
                float q = v[rt][0][j] * v[rt][0][j] + v[rt][1][j] * v[rt][1][j];
                s += __shfl_xor(s, 8); q += __shfl_xor(q, 8);
                s += __shfl_xor(s, 4); q += __shfl_xor(q, 4);
                s += __shfl_xor(s, 2); q += __shfl_xor(q, 2);
                s += __shfl_xor(s, 1); q += __shfl_xor(q, 1);
                if (lr == 0) part[w][rt * 16 + 4 * lg + j] = make_float2(s, q);
            }
        __syncthreads();
        if (t < 64) {
            const float S = part[0][t].x + part[1][t].x + part[2][t].x + part[3][t].x;
            const float Qq = part[0][t].y + part[1][t].y + part[2][t].y + part[3][t].y;
            const float mu = S * (1.f / 128.f);
            const float var = Qq * (1.f / 128.f) - mu * mu;
            lnp[t] = make_float2(mu, rsqrtf(var + 1e-5f));
        }
        __syncthreads();
#pragma unroll
        for (int rt = 0; rt < 4; ++rt) {
            const int rbase = r0 + rt * 16 + 4 * lg;
#pragma unroll
            for (int j = 0; j < 4; ++j) {
                const float2 mp = lnp[rt * 16 + 4 * lg + j];
                if (rbase + j < N) {
                    out[(size_t)(rbase + j) * 128 + col0] = (v[rt][0][j] - mp.x) * mp.y * g0 + be0;
                    out[(size_t)(rbase + j) * 128 + col1] = (v[rt][1][j] - mp.x) * mp.y * g1 + be1;
                }
            }
        }
    }
}

// ---------------------------------------------------------------------------
// Bucket build over BOTH directions (items at cnt[0..ni), users at cnt[ni..)).
// ---------------------------------------------------------------------------
__global__ __launch_bounds__(256) void hist_kernel(
    const int* __restrict__ dst_i, const int* __restrict__ dst_u,
    int* __restrict__ cnt, int ni, int E)
{
    const int e = blockIdx.x * blockDim.x + threadIdx.x;
    if (e < E) atomicAdd(&cnt[dst_i[e]], 1);
    else if (e < 2 * E) atomicAdd(&cnt[ni + dst_u[e - E]], 1);
}

__global__ __launch_bounds__(256) void alloc_kernel(
    const int* __restrict__ cnt, int* __restrict__ base,
    int* __restrict__ fill, int* __restrict__ cursor, int n)
{
    const int d = blockIdx.x * blockDim.x + threadIdx.x;
    const int lane = threadIdx.x & 63;
    int c = (d < n) ? cnt[d] : 0;
    int sc = c;
#pragma unroll
    for (int off = 1; off < 64; off <<= 1) {
        int t = __shfl_up(sc, off);
        if (lane >= off) sc += t;
    }
    const int total = __shfl(sc, 63);
    int wb = 0;
    if (lane == 63) wb = atomicAdd(cursor, total);
    wb = __shfl(wb, 63);
    if (d < n) {
        const int b = wb + sc - c;
        base[d] = b;
        fill[d] = b;
    }
}

__global__ __launch_bounds__(256) void scatter_kernel(
    const int* __restrict__ ei_ui, const int* __restrict__ ei_iu,
    int* __restrict__ fill, int* __restrict__ bucket, int ni, int E)
{
    const int e = blockIdx.x * blockDim.x + threadIdx.x;
    if (e < E) {
        const int pos = atomicAdd(&fill[ei_ui[E + e]], 1);
        bucket[pos] = ei_ui[e];
    } else if (e < 2 * E) {
        const int pos = atomicAdd(&fill[ni + ei_iu[E + e - E]], 1);
        bucket[pos] = ei_iu[e - E];
    }
}

// ---------------------------------------------------------------------------
// Gather aggregation, 4-wide predicated unroll. One wave per dst.
// ---------------------------------------------------------------------------
__global__ __launch_bounds__(256) void agg_kernel(
    const int* __restrict__ base, const int* __restrict__ cnt, const int* __restrict__ bsrc,
    const ushort* __restrict__ K, const ushort* __restrict__ Q, const ushort* __restrict__ V,
    const float* __restrict__ kwa, ushort* __restrict__ msg, int n)
{
    const int d = (int)((blockIdx.x * blockDim.x + threadIdx.x) >> 6);
    if (d >= n) return;
    const int l = threadIdx.x & 63;
    const int h = l >> 4;
    const float inv = 0.17677669529663687f;   // 1/sqrt(32)
    const uint qu = *(const uint*)&Q[(size_t)d * 128 + 2 * l];
    const float qx = bl(qu), qy = bh(qu);
    const int b = base[d], c = cnt[d];
    float mx = 0.f, my = 0.f;

    for (int i = 0; i < c; i += 4) {
        const int s0 = bsrc[b + i];
        const int s1 = (i + 1 < c) ? bsrc[b + i + 1] : s0;
        const int s2 = (i + 2 < c) ? bsrc[b + i + 2] : s0;
        const int s3 = (i + 3 < c) ? bsrc[b + i + 3] : s0;

        const uint ku0 = *(const uint*)&K[(size_t)s0 * 128 + 2 * l];
        const uint ku1 = *(const uint*)&K[(size_t)s1 * 128 + 2 * l];
        const uint ku2 = *(const uint*)&K[(size_t)s2 * 128 + 2 * l];
        const uint ku3 = *(const uint*)&K[(size_t)s3 * 128 + 2 * l];
        const uint vu0 = *(const uint*)&V[(size_t)s0 * 128 + 2 * l];
        const uint vu1 = *(const uint*)&V[(size_t)s1 * 128 + 2 * l];
        const uint vu2 = *(const uint*)&V[(size_t)s2 * 128 + 2 * l];
        const uint vu3 = *(const uint*)&V[(size_t)s3 * 128 + 2 * l];
        const float kw0 = kwa[(size_t)s0 * 4 + h];
        const float kw1 = kwa[(size_t)s1 * 4 + h];
        const float kw2 = kwa[(size_t)s2 * 4 + h];
        const float kw3 = kwa[(size_t)s3 * 4 + h];

        float p0 = bl(ku0) * qx + bh(ku0) * qy;
        float p1 = bl(ku1) * qx + bh(ku1) * qy;
        float p2 = bl(ku2) * qx + bh(ku2) * qy;
        float p3 = bl(ku3) * qx + bh(ku3) * qy;
#pragma unroll
        for (int off = 8; off; off >>= 1) {
            p0 += __shfl_xor(p0, off);
            p1 += __shfl_xor(p1, off);
            p2 += __shfl_xor(p2, off);
            p3 += __shfl_xor(p3, off);
        }
        const float e0 = __expf(p0 * inv + kw0);
        const float e1 = __expf(p1 * inv + kw1);
        const float e2 = __expf(p2 * inv + kw2);
        const float e3 = __expf(p3 * inv + kw3);
        float es0 = e0 + __shfl_xor(e0, 16);
        float es1 = e1 + __shfl_xor(e1, 16);
        float es2 = e2 + __shfl_xor(e2, 16);
        float es3 = e3 + __shfl_xor(e3, 16);
        es0 += __shfl_xor(es0, 32);
        es1 += __shfl_xor(es1, 32);
        es2 += __shfl_xor(es2, 32);
        es3 += __shfl_xor(es3, 32);
        const float a0 = __fdividef(e0, es0);
        const float a1 = (i + 1 < c) ? __fdividef(e1, es1) : 0.f;
        const float a2 = (i + 2 < c) ? __fdividef(e2, es2) : 0.f;
        const float a3 = (i + 3 < c) ? __fdividef(e3, es3) : 0.f;

        mx += a0 * bl(vu0) + a1 * bl(vu1) + a2 * bl(vu2) + a3 * bl(vu3);
        my += a0 * bh(vu0) + a1 * bh(vu1) + a2 * bh(vu2) + a3 * bh(vu3);
    }
    *(uint*)&msg[(size_t)d * 128 + 2 * l] = pk2(mx, my);
}

// ---------------------------------------------------------------------------
extern "C" void kernel_launch(void* const* d_in, const int* in_sizes, int n_in,
                              void* d_out, int out_size, void* d_ws, size_t ws_size,
                              hipStream_t stream)
{
    const float* x_user  = (const float*)d_in[0];
    const float* x_item  = (const float*)d_in[1];
    const int*   ei_ui   = (const int*)d_in[2];
    const int*   ei_iu   = (const int*)d_in[3];
    const float* Wk_user = (const float*)d_in[4];
    const float* Wq_user = (const float*)d_in[5];
    const float* Wv_user = (const float*)d_in[6];
    const float* Wk_item = (const float*)d_in[7];
    const float* Wq_item = (const float*)d_in[8];
    const float* Wv_item = (const float*)d_in[9];
    const float* Wa_ui   = (const float*)d_in[10];
    const float* Wa_iu   = (const float*)d_in[11];
    const float* Wm_user = (const float*)d_in[12];
    const float* bm_user = (const float*)d_in[13];
    const float* Wm_item = (const float*)d_in[14];
    const float* bm_item = (const float*)d_in[15];
    const float* Wg_user = (const float*)d_in[16];
    const float* bg_user = (const float*)d_in[17];
    const float* Wg_item = (const float*)d_in[18];
    const float* bg_item = (const float*)d_in[19];
    const float* lng_user = (const float*)d_in[20];
    const float* lnb_user = (const float*)d_in[21];
    const float* lng_item = (const float*)d_in[22];
    const float* lnb_item = (const float*)d_in[23];

    const int n_user = in_sizes[0] / DIM;
    const int n_item = in_sizes[1] / DIM;
    const int E = in_sizes[2] / 2;
    const int nmax = (n_user > n_item) ? n_user : n_item;
    const int ntot = n_user + n_item;
    const size_t nf = (size_t)nmax * DIM;

    ushort* Ku   = (ushort*)d_ws;       // also reused as msgB after agg item
    ushort* Qu   = Ku + nf;
    ushort* Vu   = Qu + nf;
    ushort* Ki   = Vu + nf;
    ushort* Qi   = Ki + nf;
    ushort* Vi   = Qi + nf;
    ushort* msgA = Vi + nf;
    float* kwa_u = (float*)(msgA + nf);
    float* kwa_i = kwa_u + (size_t)nmax * 4;
    int* cnt     = (int*)(kwa_i + (size_t)nmax * 4);  // [ntot] items then users
    int* cursor  = cnt + ntot;                        // [4]
    int* basep   = cursor + 4;                        // [ntot]
    int* fill    = basep + ntot;                      // [ntot]
    int* bucket  = fill + ntot;                       // [2E]
    ushort* msgB = Ku;

    float* out_user = (float*)d_out;
    float* out_item = out_user + (size_t)n_user * DIM;

    const dim3 blk(256);
    const int ntu = (n_user + 63) / 64, nti = (n_item + 63) / 64;
    const int grid_e2 = (2 * E + 255) / 256;

    hipMemsetAsync(cnt, 0, ((size_t)ntot + 4) * sizeof(int), stream);

    proj_kernel<<<ntu, blk, 0, stream>>>(x_user, Wk_user, Wq_user, Wv_user, Wa_ui, Ku, Qu, Vu, kwa_u, n_user);
    proj_kernel<<<nti, blk, 0, stream>>>(x_item, Wk_item, Wq_item, Wv_item, Wa_iu, Ki, Qi, Vi, kwa_i, n_item);

    hist_kernel<<<grid_e2, blk, 0, stream>>>(ei_ui + E, ei_iu + E, cnt, n_item, E);
    alloc_kernel<<<(ntot + 255) / 256, blk, 0, stream>>>(cnt, basep, fill, cursor, ntot);
    scatter_kernel<<<grid_e2, blk, 0, stream>>>(ei_ui, ei_iu, fill, bucket, n_item, E);

    // dst = item: K_user/V_user vs Q_item, scores use kwa_u (Wa_ui)
    agg_kernel<<<(n_item + 3) / 4, blk, 0, stream>>>(basep, cnt, bucket, Ku, Qi, Vu, kwa_u, msgA, n_item);
    // dst = user: K_item/V_item vs Q_user, scores use kwa_i (Wa_iu)
    agg_kernel<<<(n_user + 3) / 4, blk, 0, stream>>>(basep + n_item, cnt + n_item, bucket, Ki, Qu, Vi, kwa_i, msgB, n_user);

    post_kernel<<<nti, blk, 0, stream>>>(msgA, cnt, Wm_item, bm_item, Wg_item, bg_item,
                                         x_item, lng_item, lnb_item, out_item, n_item);
    post_kernel<<<ntu, blk, 0, stream>>>(msgB, cnt + n_item, Wm_user, bm_user, Wg_user, bg_user,
                                         x_user, lng_user, lnb_user, out_user, n_user);
}